// Round 10
// baseline (3475.167 us; speedup 1.0000x reference)
//
#include <hip/hip_runtime.h>
#include <math.h>

#define NU 20000
#define NI 20000
#define L  50
#define NODES 32   // per block

typedef __attribute__((ext_vector_type(8))) short bfx8;
typedef __attribute__((ext_vector_type(4))) float f32x4;
typedef unsigned short u16;
typedef unsigned char  u8;
typedef unsigned int   u32;

#define LOG2E 1.4426950408889634f

// ---- dynamic LDS layout (bytes), total 46720 (3 blocks/CU target) ----
#define OFF_H     0        // 9216: per-wave h u16[4][16][72]  (PH1 scratch: sDST u16[32][72])
#define OFF_RID   9216     // 3328: u16[32][52] sorted row ids
#define OFF_EF    12544    // 6656: f32[32][52] ted+fwd scores -> alpha
#define OFF_EB    19200    // 6656: f32[32][52] bwd scores  (PH6: sBETA u16[32][72])
#define OFF_ORD   25856    // 1664: u8[32][52]
#define OFF_ARE   27520    // 1664: u8[32][52]
#define OFF_LASTN 29184    // 128:  i32[32]
#define OFF_SCR   29312    // 17408: PH0 sTM/sNID (12800) | PH6 sHS+sA9 (17408)
#define SMEM_SZ   46720

// ---------------------------------------------------------------------------
__device__ __forceinline__ u16 f2bf(float f) {
    u32 u = __float_as_uint(f);
    u = u + 0x7fffu + ((u >> 16) & 1u);      // RNE
    return (u16)(u >> 16);
}
__device__ __forceinline__ float bf2f(u16 s) {
    return __uint_as_float(((u32)s) << 16);
}
__device__ __forceinline__ u32 cvtpk(float lo, float hi) {
    u32 d;
    asm("v_cvt_pk_bf16_f32 %0, %1, %2" : "=v"(d) : "v"(lo), "v"(hi));
    return d;
}
__device__ __forceinline__ float exp2x(float x) {
    float r;
    asm("v_exp_f32 %0, %1" : "=v"(r) : "v"(x));
    return r;
}
// args pre-scaled: sigmoid arg x -> a = x*log2e ; tanh arg y -> a = y*2*log2e
__device__ __forceinline__ float fsig2(float a) {
    return __builtin_amdgcn_rcpf(1.f + exp2x(-a));
}
__device__ __forceinline__ float ftanh2(float a) {
    return __builtin_fmaf(-2.f, __builtin_amdgcn_rcpf(exp2x(a) + 1.f), 1.f);
}
__device__ __forceinline__ bfx8 pack_bf8(const float* p) {
    float4 a = ((const float4*)p)[0];
    float4 b = ((const float4*)p)[1];
    bfx8 r;
    r[0]=(short)f2bf(a.x); r[1]=(short)f2bf(a.y); r[2]=(short)f2bf(a.z); r[3]=(short)f2bf(a.w);
    r[4]=(short)f2bf(b.x); r[5]=(short)f2bf(b.y); r[6]=(short)f2bf(b.z); r[7]=(short)f2bf(b.w);
    return r;
}

// ---------------------------------------------------------------------------
// K0: convert the 4 GRU weight matrices to bf16 with exp2 pre-scaling.
// Layout: WB[4][2][192][64]  (0=Wi_i 1=Wh_i 2=Wi_u 3=Wh_u)
// r,z rows (gate 0,1) * log2e ; n rows (gate 2) * 2*log2e.
// ---------------------------------------------------------------------------
__global__ __launch_bounds__(256) void convw_kernel(
    const float* __restrict__ Wi_i, const float* __restrict__ Wh_i,
    const float* __restrict__ Wi_u, const float* __restrict__ Wh_u,
    u16* __restrict__ o)
{
    int idx = blockIdx.x * 256 + threadIdx.x;   // 0 .. 4*24576-1
    int m   = idx / 24576, rem = idx - m * 24576;
    int row = rem >> 6;                          // 0..383
    int gate = (row % 192) >> 6;
    const float* src = (m == 0) ? Wi_i : (m == 1) ? Wh_i : (m == 2) ? Wi_u : Wh_u;
    float sc = (gate < 2) ? LOG2E : (2.f * LOG2E);
    o[idx] = f2bf(src[rem] * sc);
}

// ---------------------------------------------------------------------------
// K1: Y = X @ W.T   (also writes bf16 copy Yb)
// ---------------------------------------------------------------------------
__global__ __launch_bounds__(256) void hid_kernel(const float* __restrict__ X,
                                                  const float* __restrict__ W,
                                                  float* __restrict__ Y,
                                                  u16* __restrict__ Yb, int N)
{
    __shared__ float sW[64][65];
    int tid = threadIdx.x;
    for (int i = tid; i < 64 * 64; i += 256) sW[i >> 6][i & 63] = W[i];
    __syncthreads();
    int r = blockIdx.x * 4 + (tid >> 6);
    int d = tid & 63;
    if (r >= N) return;
    const float* x = X + (size_t)r * 64;
    float acc = 0.f;
    #pragma unroll
    for (int k = 0; k < 64; ++k) acc += x[k] * sW[d][k];
    Y[(size_t)r * 64 + d]  = acc;
    Yb[(size_t)r * 64 + d] = f2bf(acc);
}

// ---------------------------------------------------------------------------
// K3: out[r][d] = tanh( U[d][:64].A[r] + U[d][64:].F[r] )
// ---------------------------------------------------------------------------
__global__ __launch_bounds__(256) void upd_kernel(const float* __restrict__ A,
                                                  const float* __restrict__ F,
                                                  const float* __restrict__ U,
                                                  float* __restrict__ out, int N)
{
    __shared__ float sU[64][130];
    int tid = threadIdx.x;
    for (int i = tid; i < 64 * 128; i += 256) sU[i >> 7][i & 127] = U[i];
    __syncthreads();
    int r = blockIdx.x * 4 + (tid >> 6);
    int d = tid & 63;
    if (r >= N) return;
    const float* a = A + (size_t)r * 64;
    const float* f = F + (size_t)r * 64;
    float acc = 0.f;
    #pragma unroll
    for (int k = 0; k < 64; ++k) acc += a[k] * sU[d][k];
    #pragma unroll
    for (int k = 0; k < 64; ++k) acc += f[k] * sU[d][64 + k];
    out[(size_t)r * 64 + d] = tanhf(acc);
}

// ---------------------------------------------------------------------------
// K2 (merged): 1250 blocks; block < nbi -> item side, else user side.
// 32 nodes / block; wave wv: dir = wv>>1, node half (wv&1)*16. Weights are
// read per-step from global bf16 (L2-resident, pre-scaled); anti-LICM asm
// keeps them out of registers. Two passes (scores, weighted sum) as before.
// ---------------------------------------------------------------------------
__global__ __launch_bounds__(256, 3) void reduce_all(
    const u16*   __restrict__ userB,     // [NU][64] bf16
    const u16*   __restrict__ itemB,     // [NI][64] bf16
    const int*   __restrict__ i_idx,  const int*   __restrict__ i_time,
    const int*   __restrict__ u_idx,  const int*   __restrict__ u_time,
    const float* __restrict__ i_te,   const float* __restrict__ i_tek,
    const float* __restrict__ u_te,   const float* __restrict__ u_tek,
    const u16*   __restrict__ WB,        // [4][2][192][64] bf16 pre-scaled
    const float* __restrict__ i_bi,   const float* __restrict__ i_bh,
    const float* __restrict__ u_bi,   const float* __restrict__ u_bh,
    const float* __restrict__ i_glin, const float* __restrict__ u_glin,
    const float* __restrict__ i_agg,  const float* __restrict__ u_agg,
    float* __restrict__ item_out, float* __restrict__ user_out, int nbi)
{
    extern __shared__ __align__(16) char smem[];
    u16*   sRIDp  = (u16*)(smem + OFF_RID);
    float* sEF    = (float*)(smem + OFF_EF);
    float* sEB    = (float*)(smem + OFF_EB);
    u8*    sORD   = (u8*)(smem + OFF_ORD);
    u8*    sARE   = (u8*)(smem + OFF_ARE);
    int*   sLASTN = (int*)(smem + OFF_LASTN);

    const bool isU = (int)blockIdx.x >= nbi;
    const int  bid = isU ? ((int)blockIdx.x - nbi) : (int)blockIdx.x;
    const u16*   srcB     = isU ? itemB  : userB;
    const u16*   dstB     = isU ? userB  : itemB;
    const int*   nbr_idx  = isU ? u_idx  : i_idx;
    const int*   nbr_time = isU ? u_time : i_time;
    const float* te       = isU ? u_te   : i_te;
    const float* tek      = isU ? u_tek  : i_tek;
    const u16*   WiB      = WB + (size_t)(isU ? 2 : 0) * 24576;
    const u16*   WhB      = WB + (size_t)(isU ? 3 : 1) * 24576;
    const float* bi       = isU ? u_bi   : i_bi;
    const float* bh       = isU ? u_bh   : i_bh;
    const float* glin     = isU ? u_glin : i_glin;
    const float* agg      = isU ? u_agg  : i_agg;
    float*       out      = isU ? user_out : item_out;

    const int tid  = threadIdx.x;
    const int lane = tid & 63;
    const int wv   = tid >> 6;            // 0..3
    const int l15  = lane & 15;
    const int grp  = lane >> 4;           // 0..3
    const int lk8  = grp * 8;
    const int nb   = bid * NODES;
    const int dir    = wv >> 1;           // 0=fwd 1=bwd
    const int base16 = (wv & 1) * 16;     // node half owned by this wave

    u16* sHw = (u16*)(smem + OFF_H) + wv * 16 * 72;   // per-wave h [16][72]

    // ---- PH0: times/ids -> stable rank, argmax(first), sorted row ids ----
    int* sTM  = (int*)(smem + OFF_SCR);
    int* sNID = sTM + NODES * L;
    for (int p = tid; p < NODES * L; p += 256) {
        sTM[p]  = nbr_time[(size_t)nb * L + p];
        sNID[p] = nbr_idx[(size_t)nb * L + p];
    }
    __syncthreads();
    for (int p = tid; p < NODES * L; p += 256) {
        int m = p / L, l = p - m * L;
        int tl = sTM[p], rank = 0;
        for (int mm = 0; mm < L; ++mm) {
            int tm = sTM[m * L + mm];
            rank += (tm < tl) || (tm == tl && mm < l);
        }
        sORD[m * 52 + rank] = (u8)l;
        sARE[m * 52 + l]    = (u8)(L - 1 - rank);
    }
    if (tid < NODES) {
        int best = 0, bt = sTM[tid * L];
        for (int mm = 1; mm < L; ++mm) {
            int tm = sTM[tid * L + mm];
            if (tm > bt) { bt = tm; best = mm; }
        }
        sLASTN[tid] = sNID[tid * L + best];
    }
    __syncthreads();

    // ---- PH1: sorted row ids (u16) + dst staging (bf16, in H region) ----
    u16* sDST = (u16*)(smem + OFF_H);
    for (int p = tid; p < NODES * L; p += 256) {
        int m = p / L, t = p - m * L;
        sRIDp[m * 52 + t] = (u16)sNID[m * L + sORD[m * 52 + t]];
    }
    for (int p = tid; p < NODES * 64; p += 256) {
        int m = p >> 6, d = p & 63;
        sDST[m * 72 + d] = dstB[(size_t)(nb + m) * 64 + d];
    }
    __syncthreads();

    // ---- PH2a: v-GEMM (SV = vv) : v[m][j] = sum_d dst[m][d] glin[d][j] ----
    float SV[4][4];
    {
        const u16* drow = sDST + (base16 + l15) * 72;
        bfx8 a0 = *(const bfx8*)(drow + lk8);
        bfx8 a1 = *(const bfx8*)(drow + 32 + lk8);
        #pragma unroll
        for (int nt = 0; nt < 4; ++nt) {
            int j = dir * 64 + nt * 16 + l15;
            bfx8 b0, b1;
            #pragma unroll
            for (int i = 0; i < 8; ++i) {
                b0[i] = (short)f2bf(glin[(size_t)(lk8 + i) * 128 + j]);
                b1[i] = (short)f2bf(glin[(size_t)(32 + lk8 + i) * 128 + j]);
            }
            f32x4 acc = {0.f, 0.f, 0.f, 0.f};
            acc = __builtin_amdgcn_mfma_f32_16x16x32_bf16(a0, b0, acc, 0, 0, 0);
            acc = __builtin_amdgcn_mfma_f32_16x16x32_bf16(a1, b1, acc, 0, 0, 0);
            #pragma unroll
            for (int r = 0; r < 4; ++r) SV[nt][r] = acc[r];
        }
    }
    // ---- PH2b: ted GEMM, scattered directly into sEF (l = ord[L-1-j]) ----
    #pragma unroll
    for (int e2 = 0; e2 < 2; ++e2) {
        int it = wv * 2 + e2, mt = it >> 2, nt = it & 3;
        const u16* drow = sDST + (mt * 16 + l15) * 72;
        bfx8 a0 = *(const bfx8*)(drow + lk8);
        bfx8 a1 = *(const bfx8*)(drow + 32 + lk8);
        int j = nt * 16 + l15;
        const float* tr = te + (size_t)(j < L ? j : 0) * 64;
        bfx8 b0 = pack_bf8(tr + lk8);
        bfx8 b1 = pack_bf8(tr + 32 + lk8);
        f32x4 acc = {0.f, 0.f, 0.f, 0.f};
        acc = __builtin_amdgcn_mfma_f32_16x16x32_bf16(a0, b0, acc, 0, 0, 0);
        acc = __builtin_amdgcn_mfma_f32_16x16x32_bf16(a1, b1, acc, 0, 0, 0);
        if (j < L) {
            #pragma unroll
            for (int r = 0; r < 4; ++r) {
                int m = mt * 16 + grp * 4 + r;
                sEF[m * 52 + sORD[m * 52 + (L - 1 - j)]] = acc[r];
            }
        }
    }

    // ---- bias preload (pre-scaled to exp2 domain) ----
    float cb[12], pb[4];
    #pragma unroll
    for (int nt = 0; nt < 12; ++nt) {
        float bhv = bh[dir * 192 + nt * 16 + l15];
        cb[nt] = (nt < 8) ? (bi[dir * 192 + nt * 16 + l15] + bhv) * LOG2E
                          : bhv * (2.f * LOG2E);
    }
    #pragma unroll
    for (int c = 0; c < 4; ++c)
        pb[c] = bi[dir * 192 + 128 + c * 16 + l15] * (2.f * LOG2E);
    __syncthreads();

    f32x4 xcur[12];
    float hp[4][4];
    const u16* wiP = WiB + (((size_t)dir * 192 + l15) << 6) + lk8;
    const u16* whP = WhB + (((size_t)dir * 192 + l15) << 6) + lk8;

    auto produce = [&](bfx8 a0, bfx8 a1) {
        #pragma unroll
        for (int nt = 0; nt < 12; ++nt) {
            bfx8 b0 = *(const bfx8*)(wiP + nt * 1024);
            bfx8 b1 = *(const bfx8*)(wiP + nt * 1024 + 32);
            f32x4 z;
            if (nt >= 8) { float b = pb[nt - 8]; z = (f32x4){b, b, b, b}; }
            else         { z = (f32x4){0.f, 0.f, 0.f, 0.f}; }
            z = __builtin_amdgcn_mfma_f32_16x16x32_bf16(a0, b0, z, 0, 0, 0);
            z = __builtin_amdgcn_mfma_f32_16x16x32_bf16(a1, b1, z, 0, 0, 0);
            xcur[nt] = z;
        }
    };

    auto run_pass = [&](int pass) {
        #pragma unroll
        for (int c = 0; c < 4; ++c)
            #pragma unroll
            for (int r = 0; r < 4; ++r) {
                hp[c][r] = 0.f;
                if (pass == 1) SV[c][r] = 0.f;
                sHw[(grp * 4 + r) * 72 + c * 16 + l15] = 0;
            }
        {   // prologue: xw for s=0
            int tt = dir ? (L - 1) : 0;
            const u16* mrow = srcB + (size_t)sRIDp[(base16 + l15) * 52 + tt] * 64;
            produce(*(const bfx8*)(mrow + lk8), *(const bfx8*)(mrow + 32 + lk8));
        }
        for (int s = 0; s < L; ++s) {
            asm volatile("" : "+v"(wiP), "+v"(whP));   // defeat LICM of weight loads
            bfx8 nA, nB;
            if (s + 1 < L) {
                int tt = dir ? (L - 2 - s) : (s + 1);
                const u16* mrow = srcB + (size_t)sRIDp[(base16 + l15) * 52 + tt] * 64;
                nA = *(const bfx8*)(mrow + lk8);
                nB = *(const bfx8*)(mrow + 32 + lk8);
            }
            bfx8 a0 = *(const bfx8*)(sHw + l15 * 72 + lk8);
            bfx8 a1 = *(const bfx8*)(sHw + l15 * 72 + 32 + lk8);
            int t = dir ? (L - 1 - s) : s;
            float al[4];
            if (pass == 1) {
                #pragma unroll
                for (int r = 0; r < 4; ++r)
                    al[r] = sEF[(base16 + grp * 4 + r) * 52 + t];   // alpha
            }
            float pe[4] = {0.f, 0.f, 0.f, 0.f};
            #pragma unroll
            for (int c = 0; c < 4; ++c) {
                bfx8 br0 = *(const bfx8*)(whP + c * 1024);
                bfx8 br1 = *(const bfx8*)(whP + c * 1024 + 32);
                bfx8 bz0 = *(const bfx8*)(whP + (4 + c) * 1024);
                bfx8 bz1 = *(const bfx8*)(whP + (4 + c) * 1024 + 32);
                bfx8 bn0 = *(const bfx8*)(whP + (8 + c) * 1024);
                bfx8 bn1 = *(const bfx8*)(whP + (8 + c) * 1024 + 32);
                f32x4 zr  = {cb[c],     cb[c],     cb[c],     cb[c]};
                f32x4 zz4 = {cb[4 + c], cb[4 + c], cb[4 + c], cb[4 + c]};
                f32x4 zn4 = {cb[8 + c], cb[8 + c], cb[8 + c], cb[8 + c]};
                zr  = __builtin_amdgcn_mfma_f32_16x16x32_bf16(a0, br0, zr,  0, 0, 0);
                zr  = __builtin_amdgcn_mfma_f32_16x16x32_bf16(a1, br1, zr,  0, 0, 0);
                zz4 = __builtin_amdgcn_mfma_f32_16x16x32_bf16(a0, bz0, zz4, 0, 0, 0);
                zz4 = __builtin_amdgcn_mfma_f32_16x16x32_bf16(a1, bz1, zz4, 0, 0, 0);
                zn4 = __builtin_amdgcn_mfma_f32_16x16x32_bf16(a0, bn0, zn4, 0, 0, 0);
                zn4 = __builtin_amdgcn_mfma_f32_16x16x32_bf16(a1, bn1, zn4, 0, 0, 0);
                #pragma unroll
                for (int r = 0; r < 4; ++r) {
                    float rr = fsig2(xcur[c][r] + zr[r]);
                    float zz = fsig2(xcur[4 + c][r] + zz4[r]);
                    float nn = ftanh2(__builtin_fmaf(rr, zn4[r], xcur[8 + c][r]));
                    float h  = __builtin_fmaf(zz, hp[c][r] - nn, nn);
                    hp[c][r] = h;
                    if (pass == 0) pe[r] += h * SV[c][r];
                    else           SV[c][r] += al[r] * h;
                }
            }
            #pragma unroll
            for (int r = 0; r < 4; ++r) {
                u32 p0 = cvtpk(hp[0][r], hp[1][r]);
                u32 p1 = cvtpk(hp[2][r], hp[3][r]);
                u16* hb = sHw + (grp * 4 + r) * 72 + l15;
                hb[0]  = (u16)p0;  hb[16] = (u16)(p0 >> 16);
                hb[32] = (u16)p1;  hb[48] = (u16)(p1 >> 16);
            }
            if (pass == 0) {
                #pragma unroll
                for (int r = 0; r < 4; ++r) {
                    #pragma unroll
                    for (int msk = 1; msk < 16; msk <<= 1)
                        pe[r] += __shfl_xor(pe[r], msk, 64);
                }
                if (l15 == 0) {
                    #pragma unroll
                    for (int r = 0; r < 4; ++r) {
                        int idx = (base16 + grp * 4 + r) * 52 + t;
                        if (dir == 0) sEF[idx] += pe[r];
                        else          sEB[idx]  = pe[r];
                    }
                }
            }
            if (s + 1 < L) produce(nA, nB);
        }
    };

    // ---- PH3: pass 0 (scores) ----
    run_pass(0);
    __syncthreads();

    // ---- PH4: softmax; alpha overwrites sEF ----
    if (tid < NODES) {
        int m = tid;
        float mx = -1e30f;
        for (int t = 0; t < L; ++t) {
            float v = (sEF[m * 52 + t] + sEB[m * 52 + t]) * 0.125f;
            sEF[m * 52 + t] = v;
            mx = fmaxf(mx, v);
        }
        float sum = 0.f;
        for (int t = 0; t < L; ++t) {
            float ex = __expf(sEF[m * 52 + t] - mx);
            sEF[m * 52 + t] = ex;
            sum += ex;
        }
        float rs = __builtin_amdgcn_rcpf(sum);
        for (int t = 0; t < L; ++t) sEF[m * 52 + t] *= rs;
    }
    __syncthreads();

    // ---- PH5: pass 1 (weighted hidden sum) ----
    run_pass(1);
    __syncthreads();

    // ---- PH6: epilogue ----
    u16* sHS   = (u16*)(smem + OFF_SCR);         // [32][136] bf16 hsum f||b
    u16* sA9   = sHS + 32 * 136;                 // [32][136] bf16 hid || last_em
    u16* sBETA = (u16*)(smem + OFF_EB);          // [32][72]  bf16

    #pragma unroll
    for (int c = 0; c < 4; ++c)
        #pragma unroll
        for (int r = 0; r < 4; ++r)
            sHS[(base16 + grp * 4 + r) * 136 + dir * 64 + c * 16 + l15] = f2bf(SV[c][r]);
    if (tid < NODES) {
        for (int t = 0; t < L; ++t)
            sBETA[tid * 72 + sARE[tid * 52 + t]] = f2bf(sEF[tid * 52 + t]);
        for (int j = L; j < 64; ++j) sBETA[tid * 72 + j] = 0;
    }
    for (int p = tid; p < NODES * 64; p += 256) {
        int m = p >> 6, d = p & 63;
        sA9[m * 136 + 64 + d] = srcB[(size_t)sLASTN[m] * 64 + d];
    }
    __syncthreads();

    // hid[m][d] = glin[d][:].hsum[m] + te_k^T[d][:].beta[m]
    #pragma unroll
    for (int e2 = 0; e2 < 2; ++e2) {
        int it = wv * 2 + e2, mt = it >> 2, nt = it & 3;
        bfx8 aH[4], aB[2];
        #pragma unroll
        for (int kt = 0; kt < 4; ++kt)
            aH[kt] = *(const bfx8*)(sHS + (mt * 16 + l15) * 136 + kt * 32 + lk8);
        #pragma unroll
        for (int kt = 0; kt < 2; ++kt)
            aB[kt] = *(const bfx8*)(sBETA + (mt * 16 + l15) * 72 + kt * 32 + lk8);
        f32x4 acc = {0.f, 0.f, 0.f, 0.f};
        #pragma unroll
        for (int kt = 0; kt < 4; ++kt) {
            bfx8 b = pack_bf8(glin + (size_t)(nt * 16 + l15) * 128 + kt * 32 + lk8);
            acc = __builtin_amdgcn_mfma_f32_16x16x32_bf16(aH[kt], b, acc, 0, 0, 0);
        }
        #pragma unroll
        for (int kt = 0; kt < 2; ++kt) {
            bfx8 b;
            #pragma unroll
            for (int i = 0; i < 8; ++i) {
                int j = kt * 32 + lk8 + i;
                b[i] = (short)((j < L) ? f2bf(tek[(size_t)j * 64 + nt * 16 + l15]) : (u16)0);
            }
            acc = __builtin_amdgcn_mfma_f32_16x16x32_bf16(aB[kt], b, acc, 0, 0, 0);
        }
        #pragma unroll
        for (int r = 0; r < 4; ++r)
            sA9[(mt * 16 + grp * 4 + r) * 136 + nt * 16 + l15] = f2bf(acc[r]);
    }
    __syncthreads();

    // out[m][d] = agg[d][:64].hid[m] + agg[d][64:].last_em[m]
    #pragma unroll
    for (int e2 = 0; e2 < 2; ++e2) {
        int it = wv * 2 + e2, mt = it >> 2, nt = it & 3;
        bfx8 aA[4];
        #pragma unroll
        for (int kt = 0; kt < 4; ++kt)
            aA[kt] = *(const bfx8*)(sA9 + (mt * 16 + l15) * 136 + kt * 32 + lk8);
        f32x4 acc = {0.f, 0.f, 0.f, 0.f};
        #pragma unroll
        for (int kt = 0; kt < 4; ++kt) {
            bfx8 b = pack_bf8(agg + (size_t)(nt * 16 + l15) * 128 + kt * 32 + lk8);
            acc = __builtin_amdgcn_mfma_f32_16x16x32_bf16(aA[kt], b, acc, 0, 0, 0);
        }
        #pragma unroll
        for (int r = 0; r < 4; ++r)
            out[(size_t)(nb + mt * 16 + grp * 4 + r) * 64 + nt * 16 + l15] = acc[r];
    }
}

// ---------------------------------------------------------------------------
extern "C" void kernel_launch(void* const* d_in, const int* in_sizes, int n_in,
                              void* d_out, int out_size, void* d_ws, size_t ws_size,
                              hipStream_t stream)
{
    const float* user_feat     = (const float*)d_in[0];
    const float* item_feat     = (const float*)d_in[1];
    const int*   item_nbr_idx  = (const int*)d_in[2];
    const int*   item_nbr_time = (const int*)d_in[3];
    const int*   user_nbr_idx  = (const int*)d_in[4];
    const int*   user_nbr_time = (const int*)d_in[5];
    const float* W_user        = (const float*)d_in[6];
    const float* W_item        = (const float*)d_in[7];
    const float* u_te          = (const float*)d_in[8];
    const float* u_te_k        = (const float*)d_in[9];
    const float* i_te          = (const float*)d_in[10];
    const float* i_te_k        = (const float*)d_in[11];
    const float* gru_u_Wi      = (const float*)d_in[12];
    const float* gru_u_Wh      = (const float*)d_in[13];
    const float* gru_u_bi      = (const float*)d_in[14];
    const float* gru_u_bh      = (const float*)d_in[15];
    const float* gru_i_Wi      = (const float*)d_in[16];
    const float* gru_i_Wh      = (const float*)d_in[17];
    const float* gru_i_bi      = (const float*)d_in[18];
    const float* gru_i_bh      = (const float*)d_in[19];
    const float* gru_lin_u     = (const float*)d_in[20];
    const float* gru_lin_i     = (const float*)d_in[21];
    const float* agg_u         = (const float*)d_in[22];
    const float* agg_i         = (const float*)d_in[23];
    const float* upd_u         = (const float*)d_in[24];
    const float* upd_i         = (const float*)d_in[25];

    float* ws       = (float*)d_ws;
    float* user_hid = ws;
    float* item_hid = user_hid + NU * 64;
    float* item_agg = item_hid + NI * 64;
    float* user_agg = item_agg + NI * 64;
    u16*   userB    = (u16*)(user_agg + NU * 64);
    u16*   itemB    = userB + NU * 64;
    u16*   WB       = itemB + NI * 64;      // [4][2][192][64] bf16

    (void)hipFuncSetAttribute((const void*)reduce_all,
                              hipFuncAttributeMaxDynamicSharedMemorySize, SMEM_SZ);

    convw_kernel<<<384, 256, 0, stream>>>(gru_i_Wi, gru_i_Wh, gru_u_Wi, gru_u_Wh, WB);
    hid_kernel<<<NU / 4, 256, 0, stream>>>(user_feat, W_user, user_hid, userB, NU);
    hid_kernel<<<NI / 4, 256, 0, stream>>>(item_feat, W_item, item_hid, itemB, NI);

    const int NBI = NI / NODES;     // 625 item-side blocks, then 625 user-side
    reduce_all<<<NBI + NU / NODES, 256, SMEM_SZ, stream>>>(
        userB, itemB,
        item_nbr_idx, item_nbr_time, user_nbr_idx, user_nbr_time,
        i_te, i_te_k, u_te, u_te_k,
        WB,
        gru_i_bi, gru_i_bh, gru_u_bi, gru_u_bh,
        gru_lin_i, gru_lin_u, agg_i, agg_u,
        item_agg, user_agg, NBI);

    float* out = (float*)d_out;
    upd_kernel<<<NU / 4, 256, 0, stream>>>(user_agg, user_feat, upd_u, out, NU);
    upd_kernel<<<NI / 4, 256, 0, stream>>>(item_agg, item_feat, upd_i, out + NU * 64, NI);
}

// Round 11
// 2873.117 us; speedup vs baseline: 1.2095x; 1.2095x over previous
//
#include <hip/hip_runtime.h>
#include <math.h>

#define NU 20000
#define NI 20000
#define L  50
#define NODES 32   // per block

typedef __attribute__((ext_vector_type(8))) short bfx8;
typedef __attribute__((ext_vector_type(4))) float f32x4;
typedef unsigned short u16;
typedef unsigned char  u8;
typedef unsigned int   u32;

#define LOG2E 1.4426950408889634f

// ---- dynamic LDS layout (bytes), total 46720 (3 blocks/CU target) ----
#define OFF_H     0        // 9216: per-wave h u16[4][16][72]  (PH1 scratch: sDST u16[32][72])
#define OFF_RID   9216     // 3328: u16[32][52] sorted row ids
#define OFF_EF    12544    // 6656: f32[32][52] ted+fwd scores -> alpha
#define OFF_EB    19200    // 6656: f32[32][52] bwd scores  (PH6: sBETA u16[32][72])
#define OFF_ORD   25856    // 1664: u8[32][52]
#define OFF_ARE   27520    // 1664: u8[32][52]
#define OFF_LASTN 29184    // 128:  i32[32]
#define OFF_SCR   29312    // 17408: PH0 sTM/sNID (12800) | PH6 sHS+sA9 (17408)
#define SMEM_SZ   46720

// ---------------------------------------------------------------------------
__device__ __forceinline__ u16 f2bf(float f) {
    u32 u = __float_as_uint(f);
    u = u + 0x7fffu + ((u >> 16) & 1u);      // RNE
    return (u16)(u >> 16);
}
__device__ __forceinline__ float bflo(u32 u) { return __uint_as_float(u << 16); }
__device__ __forceinline__ float bfhi(u32 u) { return __uint_as_float(u & 0xffff0000u); }
__device__ __forceinline__ u32 cvtpk(float lo, float hi) {
    u32 d;
    asm("v_cvt_pk_bf16_f32 %0, %1, %2" : "=v"(d) : "v"(lo), "v"(hi));
    return d;
}
__device__ __forceinline__ float exp2x(float x) {
    float r;
    asm("v_exp_f32 %0, %1" : "=v"(r) : "v"(x));
    return r;
}
// args pre-scaled: sigmoid arg x -> a = x*log2e ; tanh arg y -> a = y*2*log2e
__device__ __forceinline__ float fsig2(float a) {
    return __builtin_amdgcn_rcpf(1.f + exp2x(-a));
}
__device__ __forceinline__ float ftanh2(float a) {
    return __builtin_fmaf(-2.f, __builtin_amdgcn_rcpf(exp2x(a) + 1.f), 1.f);
}
__device__ __forceinline__ float xget(uint2 u, int r) {
    switch (r) {
        case 0: return bflo(u.x);
        case 1: return bfhi(u.x);
        case 2: return bflo(u.y);
        default: return bfhi(u.y);
    }
}
__device__ __forceinline__ bfx8 pack_bf8(const float* p) {
    float4 a = ((const float4*)p)[0];
    float4 b = ((const float4*)p)[1];
    bfx8 r;
    r[0]=(short)f2bf(a.x); r[1]=(short)f2bf(a.y); r[2]=(short)f2bf(a.z); r[3]=(short)f2bf(a.w);
    r[4]=(short)f2bf(b.x); r[5]=(short)f2bf(b.y); r[6]=(short)f2bf(b.z); r[7]=(short)f2bf(b.w);
    return r;
}

// ---------------------------------------------------------------------------
// K0: convert the 4 GRU weight matrices to bf16 with exp2 pre-scaling.
// Layout: WB[4][2][192][64]  (0=Wi_i 1=Wh_i 2=Wi_u 3=Wh_u)
// r,z rows (gate 0,1) * log2e ; n rows (gate 2) * 2*log2e.
// ---------------------------------------------------------------------------
__global__ __launch_bounds__(256) void convw_kernel(
    const float* __restrict__ Wi_i, const float* __restrict__ Wh_i,
    const float* __restrict__ Wi_u, const float* __restrict__ Wh_u,
    u16* __restrict__ o)
{
    int idx = blockIdx.x * 256 + threadIdx.x;   // 0 .. 4*24576-1
    int m   = idx / 24576, rem = idx - m * 24576;
    int row = rem >> 6;                          // 0..383
    int gate = (row % 192) >> 6;
    const float* src = (m == 0) ? Wi_i : (m == 1) ? Wh_i : (m == 2) ? Wi_u : Wh_u;
    float sc = (gate < 2) ? LOG2E : (2.f * LOG2E);
    o[idx] = f2bf(src[rem] * sc);
}

// ---------------------------------------------------------------------------
// K1: Y = X @ W.T   (also writes bf16 copy Yb)
// ---------------------------------------------------------------------------
__global__ __launch_bounds__(256) void hid_kernel(const float* __restrict__ X,
                                                  const float* __restrict__ W,
                                                  float* __restrict__ Y,
                                                  u16* __restrict__ Yb, int N)
{
    __shared__ float sW[64][65];
    int tid = threadIdx.x;
    for (int i = tid; i < 64 * 64; i += 256) sW[i >> 6][i & 63] = W[i];
    __syncthreads();
    int r = blockIdx.x * 4 + (tid >> 6);
    int d = tid & 63;
    if (r >= N) return;
    const float* x = X + (size_t)r * 64;
    float acc = 0.f;
    #pragma unroll
    for (int k = 0; k < 64; ++k) acc += x[k] * sW[d][k];
    Y[(size_t)r * 64 + d]  = acc;
    Yb[(size_t)r * 64 + d] = f2bf(acc);
}

// ---------------------------------------------------------------------------
// K3: out[r][d] = tanh( U[d][:64].A[r] + U[d][64:].F[r] )
// ---------------------------------------------------------------------------
__global__ __launch_bounds__(256) void upd_kernel(const float* __restrict__ A,
                                                  const float* __restrict__ F,
                                                  const float* __restrict__ U,
                                                  float* __restrict__ out, int N)
{
    __shared__ float sU[64][130];
    int tid = threadIdx.x;
    for (int i = tid; i < 64 * 128; i += 256) sU[i >> 7][i & 127] = U[i];
    __syncthreads();
    int r = blockIdx.x * 4 + (tid >> 6);
    int d = tid & 63;
    if (r >= N) return;
    const float* a = A + (size_t)r * 64;
    const float* f = F + (size_t)r * 64;
    float acc = 0.f;
    #pragma unroll
    for (int k = 0; k < 64; ++k) acc += a[k] * sU[d][k];
    #pragma unroll
    for (int k = 0; k < 64; ++k) acc += f[k] * sU[d][64 + k];
    out[(size_t)r * 64 + d] = tanhf(acc);
}

// ---------------------------------------------------------------------------
// K2 (merged): 1250 blocks; block < nbi -> item side, else user side.
// 32 nodes / block; wave wv: dir = wv>>1, node half (wv&1)*16. Weights are
// read per-step from global bf16 (L2-resident, pre-scaled); anti-LICM asm
// keeps them out of registers. xw is bf16-packed (uint2[12], 24 VGPR) to
// keep total VGPR in the 3-waves/SIMD tier (<=170). NO min-waves bound:
// forcing it (rounds 5/6/9) makes the allocator spill loop-invariants.
// ---------------------------------------------------------------------------
__global__ __launch_bounds__(256) void reduce_all(
    const u16*   __restrict__ userB,     // [NU][64] bf16
    const u16*   __restrict__ itemB,     // [NI][64] bf16
    const int*   __restrict__ i_idx,  const int*   __restrict__ i_time,
    const int*   __restrict__ u_idx,  const int*   __restrict__ u_time,
    const float* __restrict__ i_te,   const float* __restrict__ i_tek,
    const float* __restrict__ u_te,   const float* __restrict__ u_tek,
    const u16*   __restrict__ WB,        // [4][2][192][64] bf16 pre-scaled
    const float* __restrict__ i_bi,   const float* __restrict__ i_bh,
    const float* __restrict__ u_bi,   const float* __restrict__ u_bh,
    const float* __restrict__ i_glin, const float* __restrict__ u_glin,
    const float* __restrict__ i_agg,  const float* __restrict__ u_agg,
    float* __restrict__ item_out, float* __restrict__ user_out, int nbi)
{
    extern __shared__ __align__(16) char smem[];
    u16*   sRIDp  = (u16*)(smem + OFF_RID);
    float* sEF    = (float*)(smem + OFF_EF);
    float* sEB    = (float*)(smem + OFF_EB);
    u8*    sORD   = (u8*)(smem + OFF_ORD);
    u8*    sARE   = (u8*)(smem + OFF_ARE);
    int*   sLASTN = (int*)(smem + OFF_LASTN);

    const bool isU = (int)blockIdx.x >= nbi;
    const int  bid = isU ? ((int)blockIdx.x - nbi) : (int)blockIdx.x;
    const u16*   srcB     = isU ? itemB  : userB;
    const u16*   dstB     = isU ? userB  : itemB;
    const int*   nbr_idx  = isU ? u_idx  : i_idx;
    const int*   nbr_time = isU ? u_time : i_time;
    const float* te       = isU ? u_te   : i_te;
    const float* tek      = isU ? u_tek  : i_tek;
    const u16*   WiB      = WB + (size_t)(isU ? 2 : 0) * 24576;
    const u16*   WhB      = WB + (size_t)(isU ? 3 : 1) * 24576;
    const float* bi       = isU ? u_bi   : i_bi;
    const float* bh       = isU ? u_bh   : i_bh;
    const float* glin     = isU ? u_glin : i_glin;
    const float* agg      = isU ? u_agg  : i_agg;
    float*       out      = isU ? user_out : item_out;

    const int tid  = threadIdx.x;
    const int lane = tid & 63;
    const int wv   = tid >> 6;            // 0..3
    const int l15  = lane & 15;
    const int grp  = lane >> 4;           // 0..3
    const int lk8  = grp * 8;
    const int nb   = bid * NODES;
    const int dir    = wv >> 1;           // 0=fwd 1=bwd
    const int base16 = (wv & 1) * 16;     // node half owned by this wave

    u16* sHw = (u16*)(smem + OFF_H) + wv * 16 * 72;   // per-wave h [16][72]

    // ---- PH0: times/ids -> stable rank, argmax(first), sorted row ids ----
    int* sTM  = (int*)(smem + OFF_SCR);
    int* sNID = sTM + NODES * L;
    for (int p = tid; p < NODES * L; p += 256) {
        sTM[p]  = nbr_time[(size_t)nb * L + p];
        sNID[p] = nbr_idx[(size_t)nb * L + p];
    }
    __syncthreads();
    for (int p = tid; p < NODES * L; p += 256) {
        int m = p / L, l = p - m * L;
        int tl = sTM[p], rank = 0;
        for (int mm = 0; mm < L; ++mm) {
            int tm = sTM[m * L + mm];
            rank += (tm < tl) || (tm == tl && mm < l);
        }
        sORD[m * 52 + rank] = (u8)l;
        sARE[m * 52 + l]    = (u8)(L - 1 - rank);
    }
    if (tid < NODES) {
        int best = 0, bt = sTM[tid * L];
        for (int mm = 1; mm < L; ++mm) {
            int tm = sTM[tid * L + mm];
            if (tm > bt) { bt = tm; best = mm; }
        }
        sLASTN[tid] = sNID[tid * L + best];
    }
    __syncthreads();

    // ---- PH1: sorted row ids (u16) + dst staging (bf16, in H region) ----
    u16* sDST = (u16*)(smem + OFF_H);
    for (int p = tid; p < NODES * L; p += 256) {
        int m = p / L, t = p - m * L;
        sRIDp[m * 52 + t] = (u16)sNID[m * L + sORD[m * 52 + t]];
    }
    for (int p = tid; p < NODES * 64; p += 256) {
        int m = p >> 6, d = p & 63;
        sDST[m * 72 + d] = dstB[(size_t)(nb + m) * 64 + d];
    }
    __syncthreads();

    // ---- PH2a: v-GEMM (SV = vv) : v[m][j] = sum_d dst[m][d] glin[d][j] ----
    float SV[4][4];
    {
        const u16* drow = sDST + (base16 + l15) * 72;
        bfx8 a0 = *(const bfx8*)(drow + lk8);
        bfx8 a1 = *(const bfx8*)(drow + 32 + lk8);
        #pragma unroll
        for (int nt = 0; nt < 4; ++nt) {
            int j = dir * 64 + nt * 16 + l15;
            bfx8 b0, b1;
            #pragma unroll
            for (int i = 0; i < 8; ++i) {
                b0[i] = (short)f2bf(glin[(size_t)(lk8 + i) * 128 + j]);
                b1[i] = (short)f2bf(glin[(size_t)(32 + lk8 + i) * 128 + j]);
            }
            f32x4 acc = {0.f, 0.f, 0.f, 0.f};
            acc = __builtin_amdgcn_mfma_f32_16x16x32_bf16(a0, b0, acc, 0, 0, 0);
            acc = __builtin_amdgcn_mfma_f32_16x16x32_bf16(a1, b1, acc, 0, 0, 0);
            #pragma unroll
            for (int r = 0; r < 4; ++r) SV[nt][r] = acc[r];
        }
    }
    // ---- PH2b: ted GEMM, scattered directly into sEF (l = ord[L-1-j]) ----
    #pragma unroll
    for (int e2 = 0; e2 < 2; ++e2) {
        int it = wv * 2 + e2, mt = it >> 2, nt = it & 3;
        const u16* drow = sDST + (mt * 16 + l15) * 72;
        bfx8 a0 = *(const bfx8*)(drow + lk8);
        bfx8 a1 = *(const bfx8*)(drow + 32 + lk8);
        int j = nt * 16 + l15;
        const float* tr = te + (size_t)(j < L ? j : 0) * 64;
        bfx8 b0 = pack_bf8(tr + lk8);
        bfx8 b1 = pack_bf8(tr + 32 + lk8);
        f32x4 acc = {0.f, 0.f, 0.f, 0.f};
        acc = __builtin_amdgcn_mfma_f32_16x16x32_bf16(a0, b0, acc, 0, 0, 0);
        acc = __builtin_amdgcn_mfma_f32_16x16x32_bf16(a1, b1, acc, 0, 0, 0);
        if (j < L) {
            #pragma unroll
            for (int r = 0; r < 4; ++r) {
                int m = mt * 16 + grp * 4 + r;
                sEF[m * 52 + sORD[m * 52 + (L - 1 - j)]] = acc[r];
            }
        }
    }

    // ---- bias preload (pre-scaled to exp2 domain) ----
    float cb[12], pb[4];
    #pragma unroll
    for (int nt = 0; nt < 12; ++nt) {
        float bhv = bh[dir * 192 + nt * 16 + l15];
        cb[nt] = (nt < 8) ? (bi[dir * 192 + nt * 16 + l15] + bhv) * LOG2E
                          : bhv * (2.f * LOG2E);
    }
    #pragma unroll
    for (int c = 0; c < 4; ++c)
        pb[c] = bi[dir * 192 + 128 + c * 16 + l15] * (2.f * LOG2E);
    __syncthreads();

    uint2 xcur[12];
    float hp[4][4];
    const u16* wiP = WiB + (((size_t)dir * 192 + l15) << 6) + lk8;
    const u16* whP = WhB + (((size_t)dir * 192 + l15) << 6) + lk8;

    auto produce = [&](bfx8 a0, bfx8 a1) {
        #pragma unroll
        for (int nt = 0; nt < 12; ++nt) {
            bfx8 b0 = *(const bfx8*)(wiP + nt * 1024);
            bfx8 b1 = *(const bfx8*)(wiP + nt * 1024 + 32);
            f32x4 z;
            if (nt >= 8) { float b = pb[nt - 8]; z = (f32x4){b, b, b, b}; }
            else         { z = (f32x4){0.f, 0.f, 0.f, 0.f}; }
            z = __builtin_amdgcn_mfma_f32_16x16x32_bf16(a0, b0, z, 0, 0, 0);
            z = __builtin_amdgcn_mfma_f32_16x16x32_bf16(a1, b1, z, 0, 0, 0);
            uint2 pk;
            pk.x = cvtpk(z[0], z[1]);
            pk.y = cvtpk(z[2], z[3]);
            xcur[nt] = pk;
        }
    };

    auto run_pass = [&](int pass) {
        #pragma unroll
        for (int c = 0; c < 4; ++c)
            #pragma unroll
            for (int r = 0; r < 4; ++r) {
                hp[c][r] = 0.f;
                if (pass == 1) SV[c][r] = 0.f;
                sHw[(grp * 4 + r) * 72 + c * 16 + l15] = 0;
            }
        {   // prologue: xw for s=0
            int tt = dir ? (L - 1) : 0;
            const u16* mrow = srcB + (size_t)sRIDp[(base16 + l15) * 52 + tt] * 64;
            produce(*(const bfx8*)(mrow + lk8), *(const bfx8*)(mrow + 32 + lk8));
        }
        for (int s = 0; s < L; ++s) {
            asm volatile("" : "+v"(wiP), "+v"(whP));   // defeat LICM of weight loads
            bfx8 nA, nB;
            if (s + 1 < L) {
                int tt = dir ? (L - 2 - s) : (s + 1);
                const u16* mrow = srcB + (size_t)sRIDp[(base16 + l15) * 52 + tt] * 64;
                nA = *(const bfx8*)(mrow + lk8);
                nB = *(const bfx8*)(mrow + 32 + lk8);
            }
            bfx8 a0 = *(const bfx8*)(sHw + l15 * 72 + lk8);
            bfx8 a1 = *(const bfx8*)(sHw + l15 * 72 + 32 + lk8);
            int t = dir ? (L - 1 - s) : s;
            float al[4];
            if (pass == 1) {
                #pragma unroll
                for (int r = 0; r < 4; ++r)
                    al[r] = sEF[(base16 + grp * 4 + r) * 52 + t];   // alpha
            }
            float pe[4] = {0.f, 0.f, 0.f, 0.f};
            #pragma unroll
            for (int c = 0; c < 4; ++c) {
                bfx8 br0 = *(const bfx8*)(whP + c * 1024);
                bfx8 br1 = *(const bfx8*)(whP + c * 1024 + 32);
                bfx8 bz0 = *(const bfx8*)(whP + (4 + c) * 1024);
                bfx8 bz1 = *(const bfx8*)(whP + (4 + c) * 1024 + 32);
                bfx8 bn0 = *(const bfx8*)(whP + (8 + c) * 1024);
                bfx8 bn1 = *(const bfx8*)(whP + (8 + c) * 1024 + 32);
                f32x4 zr  = {cb[c],     cb[c],     cb[c],     cb[c]};
                f32x4 zz4 = {cb[4 + c], cb[4 + c], cb[4 + c], cb[4 + c]};
                f32x4 zn4 = {cb[8 + c], cb[8 + c], cb[8 + c], cb[8 + c]};
                zr  = __builtin_amdgcn_mfma_f32_16x16x32_bf16(a0, br0, zr,  0, 0, 0);
                zr  = __builtin_amdgcn_mfma_f32_16x16x32_bf16(a1, br1, zr,  0, 0, 0);
                zz4 = __builtin_amdgcn_mfma_f32_16x16x32_bf16(a0, bz0, zz4, 0, 0, 0);
                zz4 = __builtin_amdgcn_mfma_f32_16x16x32_bf16(a1, bz1, zz4, 0, 0, 0);
                zn4 = __builtin_amdgcn_mfma_f32_16x16x32_bf16(a0, bn0, zn4, 0, 0, 0);
                zn4 = __builtin_amdgcn_mfma_f32_16x16x32_bf16(a1, bn1, zn4, 0, 0, 0);
                #pragma unroll
                for (int r = 0; r < 4; ++r) {
                    float rr = fsig2(xget(xcur[c], r) + zr[r]);
                    float zz = fsig2(xget(xcur[4 + c], r) + zz4[r]);
                    float nn = ftanh2(__builtin_fmaf(rr, zn4[r], xget(xcur[8 + c], r)));
                    float h  = __builtin_fmaf(zz, hp[c][r] - nn, nn);
                    hp[c][r] = h;
                    if (pass == 0) pe[r] += h * SV[c][r];
                    else           SV[c][r] += al[r] * h;
                }
            }
            #pragma unroll
            for (int r = 0; r < 4; ++r) {
                u32 p0 = cvtpk(hp[0][r], hp[1][r]);
                u32 p1 = cvtpk(hp[2][r], hp[3][r]);
                u16* hb = sHw + (grp * 4 + r) * 72 + l15;
                hb[0]  = (u16)p0;  hb[16] = (u16)(p0 >> 16);
                hb[32] = (u16)p1;  hb[48] = (u16)(p1 >> 16);
            }
            if (pass == 0) {
                #pragma unroll
                for (int r = 0; r < 4; ++r) {
                    #pragma unroll
                    for (int msk = 1; msk < 16; msk <<= 1)
                        pe[r] += __shfl_xor(pe[r], msk, 64);
                }
                if (l15 == 0) {
                    #pragma unroll
                    for (int r = 0; r < 4; ++r) {
                        int idx = (base16 + grp * 4 + r) * 52 + t;
                        if (dir == 0) sEF[idx] += pe[r];
                        else          sEB[idx]  = pe[r];
                    }
                }
            }
            if (s + 1 < L) produce(nA, nB);
        }
    };

    // ---- PH3: pass 0 (scores) ----
    run_pass(0);
    __syncthreads();

    // ---- PH4: softmax; alpha overwrites sEF ----
    if (tid < NODES) {
        int m = tid;
        float mx = -1e30f;
        for (int t = 0; t < L; ++t) {
            float v = (sEF[m * 52 + t] + sEB[m * 52 + t]) * 0.125f;
            sEF[m * 52 + t] = v;
            mx = fmaxf(mx, v);
        }
        float sum = 0.f;
        for (int t = 0; t < L; ++t) {
            float ex = __expf(sEF[m * 52 + t] - mx);
            sEF[m * 52 + t] = ex;
            sum += ex;
        }
        float rs = __builtin_amdgcn_rcpf(sum);
        for (int t = 0; t < L; ++t) sEF[m * 52 + t] *= rs;
    }
    __syncthreads();

    // ---- PH5: pass 1 (weighted hidden sum) ----
    run_pass(1);
    __syncthreads();

    // ---- PH6: epilogue ----
    u16* sHS   = (u16*)(smem + OFF_SCR);         // [32][136] bf16 hsum f||b
    u16* sA9   = sHS + 32 * 136;                 // [32][136] bf16 hid || last_em
    u16* sBETA = (u16*)(smem + OFF_EB);          // [32][72]  bf16

    #pragma unroll
    for (int c = 0; c < 4; ++c)
        #pragma unroll
        for (int r = 0; r < 4; ++r)
            sHS[(base16 + grp * 4 + r) * 136 + dir * 64 + c * 16 + l15] = f2bf(SV[c][r]);
    if (tid < NODES) {
        for (int t = 0; t < L; ++t)
            sBETA[tid * 72 + sARE[tid * 52 + t]] = f2bf(sEF[tid * 52 + t]);
        for (int j = L; j < 64; ++j) sBETA[tid * 72 + j] = 0;
    }
    for (int p = tid; p < NODES * 64; p += 256) {
        int m = p >> 6, d = p & 63;
        sA9[m * 136 + 64 + d] = srcB[(size_t)sLASTN[m] * 64 + d];
    }
    __syncthreads();

    // hid[m][d] = glin[d][:].hsum[m] + te_k^T[d][:].beta[m]
    #pragma unroll
    for (int e2 = 0; e2 < 2; ++e2) {
        int it = wv * 2 + e2, mt = it >> 2, nt = it & 3;
        bfx8 aH[4], aB[2];
        #pragma unroll
        for (int kt = 0; kt < 4; ++kt)
            aH[kt] = *(const bfx8*)(sHS + (mt * 16 + l15) * 136 + kt * 32 + lk8);
        #pragma unroll
        for (int kt = 0; kt < 2; ++kt)
            aB[kt] = *(const bfx8*)(sBETA + (mt * 16 + l15) * 72 + kt * 32 + lk8);
        f32x4 acc = {0.f, 0.f, 0.f, 0.f};
        #pragma unroll
        for (int kt = 0; kt < 4; ++kt) {
            bfx8 b = pack_bf8(glin + (size_t)(nt * 16 + l15) * 128 + kt * 32 + lk8);
            acc = __builtin_amdgcn_mfma_f32_16x16x32_bf16(aH[kt], b, acc, 0, 0, 0);
        }
        #pragma unroll
        for (int kt = 0; kt < 2; ++kt) {
            bfx8 b;
            #pragma unroll
            for (int i = 0; i < 8; ++i) {
                int j = kt * 32 + lk8 + i;
                b[i] = (short)((j < L) ? f2bf(tek[(size_t)j * 64 + nt * 16 + l15]) : (u16)0);
            }
            acc = __builtin_amdgcn_mfma_f32_16x16x32_bf16(aB[kt], b, acc, 0, 0, 0);
        }
        #pragma unroll
        for (int r = 0; r < 4; ++r)
            sA9[(mt * 16 + grp * 4 + r) * 136 + nt * 16 + l15] = f2bf(acc[r]);
    }
    __syncthreads();

    // out[m][d] = agg[d][:64].hid[m] + agg[d][64:].last_em[m]
    #pragma unroll
    for (int e2 = 0; e2 < 2; ++e2) {
        int it = wv * 2 + e2, mt = it >> 2, nt = it & 3;
        bfx8 aA[4];
        #pragma unroll
        for (int kt = 0; kt < 4; ++kt)
            aA[kt] = *(const bfx8*)(sA9 + (mt * 16 + l15) * 136 + kt * 32 + lk8);
        f32x4 acc = {0.f, 0.f, 0.f, 0.f};
        #pragma unroll
        for (int kt = 0; kt < 4; ++kt) {
            bfx8 b = pack_bf8(agg + (size_t)(nt * 16 + l15) * 128 + kt * 32 + lk8);
            acc = __builtin_amdgcn_mfma_f32_16x16x32_bf16(aA[kt], b, acc, 0, 0, 0);
        }
        #pragma unroll
        for (int r = 0; r < 4; ++r)
            out[(size_t)(nb + mt * 16 + grp * 4 + r) * 64 + nt * 16 + l15] = acc[r];
    }
}

// ---------------------------------------------------------------------------
extern "C" void kernel_launch(void* const* d_in, const int* in_sizes, int n_in,
                              void* d_out, int out_size, void* d_ws, size_t ws_size,
                              hipStream_t stream)
{
    const float* user_feat     = (const float*)d_in[0];
    const float* item_feat     = (const float*)d_in[1];
    const int*   item_nbr_idx  = (const int*)d_in[2];
    const int*   item_nbr_time = (const int*)d_in[3];
    const int*   user_nbr_idx  = (const int*)d_in[4];
    const int*   user_nbr_time = (const int*)d_in[5];
    const float* W_user        = (const float*)d_in[6];
    const float* W_item        = (const float*)d_in[7];
    const float* u_te          = (const float*)d_in[8];
    const float* u_te_k        = (const float*)d_in[9];
    const float* i_te          = (const float*)d_in[10];
    const float* i_te_k        = (const float*)d_in[11];
    const float* gru_u_Wi      = (const float*)d_in[12];
    const float* gru_u_Wh      = (const float*)d_in[13];
    const float* gru_u_bi      = (const float*)d_in[14];
    const float* gru_u_bh      = (const float*)d_in[15];
    const float* gru_i_Wi      = (const float*)d_in[16];
    const float* gru_i_Wh      = (const float*)d_in[17];
    const float* gru_i_bi      = (const float*)d_in[18];
    const float* gru_i_bh      = (const float*)d_in[19];
    const float* gru_lin_u     = (const float*)d_in[20];
    const float* gru_lin_i     = (const float*)d_in[21];
    const float* agg_u         = (const float*)d_in[22];
    const float* agg_i         = (const float*)d_in[23];
    const float* upd_u         = (const float*)d_in[24];
    const float* upd_i         = (const float*)d_in[25];

    float* ws       = (float*)d_ws;
    float* user_hid = ws;
    float* item_hid = user_hid + NU * 64;
    float* item_agg = item_hid + NI * 64;
    float* user_agg = item_agg + NI * 64;
    u16*   userB    = (u16*)(user_agg + NU * 64);
    u16*   itemB    = userB + NU * 64;
    u16*   WB       = itemB + NI * 64;      // [4][2][192][64] bf16

    (void)hipFuncSetAttribute((const void*)reduce_all,
                              hipFuncAttributeMaxDynamicSharedMemorySize, SMEM_SZ);

    convw_kernel<<<384, 256, 0, stream>>>(gru_i_Wi, gru_i_Wh, gru_u_Wi, gru_u_Wh, WB);
    hid_kernel<<<NU / 4, 256, 0, stream>>>(user_feat, W_user, user_hid, userB, NU);
    hid_kernel<<<NI / 4, 256, 0, stream>>>(item_feat, W_item, item_hid, itemB, NI);

    const int NBI = NI / NODES;     // 625 item-side blocks, then 625 user-side
    reduce_all<<<NBI + NU / NODES, 256, SMEM_SZ, stream>>>(
        userB, itemB,
        item_nbr_idx, item_nbr_time, user_nbr_idx, user_nbr_time,
        i_te, i_te_k, u_te, u_te_k,
        WB,
        gru_i_bi, gru_i_bh, gru_u_bi, gru_u_bh,
        gru_lin_i, gru_lin_u, agg_i, agg_u,
        item_agg, user_agg, NBI);

    float* out = (float*)d_out;
    upd_kernel<<<NU / 4, 256, 0, stream>>>(user_agg, user_feat, upd_u, out, NU);
    upd_kernel<<<NI / 4, 256, 0, stream>>>(item_agg, item_feat, upd_i, out + NU * 64, NI);
}

// Round 12
// 1187.199 us; speedup vs baseline: 2.9272x; 2.4201x over previous
//
#include <hip/hip_runtime.h>
#include <math.h>

#define NU 20000
#define NI 20000
#define L  50
#define NODES 32   // per block

typedef __attribute__((ext_vector_type(8))) short bfx8;
typedef __attribute__((ext_vector_type(4))) float f32x4;
typedef unsigned short u16;
typedef unsigned char  u8;
typedef unsigned int   u32;

#define LOG2E 1.4426950408889634f

// ---- dynamic LDS layout (bytes), total 78464 (2 blocks/CU, LDS-capped) ----
#define OFF_WI    0        // 49152: Wi blocked+swizzled+prescaled [2][2][192][32]bf16
                           //   PH0 scratch: sTM/sNID (12800); PH2 scratch: sGLT (18432)
                           //   PH6 scratch: sHS[32][136] + sA9[32][136] + sTKT[64][72]
#define OFF_H     49152    // 9216: per-wave h u16[4][16][72]  (PH1 scratch: sDST u16[32][72])
#define OFF_RID   58368    // 3328: u16[32][52] sorted row ids
#define OFF_EF    61696    // 6656: f32[32][52] ted+fwd scores -> alpha
#define OFF_EB    68352    // 6656: f32[32][52] bwd scores  (PH6: sBETA u16[32][72])
#define OFF_ORD   75008    // 1664: u8[32][52]
#define OFF_ARE   76672    // 1664: u8[32][52]
#define OFF_LASTN 78336    // 128:  i32[32]
#define SMEM_SZ   78464

// ---------------------------------------------------------------------------
__device__ __forceinline__ u16 f2bf(float f) {
    u32 u = __float_as_uint(f);
    u = u + 0x7fffu + ((u >> 16) & 1u);      // RNE
    return (u16)(u >> 16);
}
__device__ __forceinline__ float bflo(u32 u) { return __uint_as_float(u << 16); }
__device__ __forceinline__ float bfhi(u32 u) { return __uint_as_float(u & 0xffff0000u); }
__device__ __forceinline__ u32 cvtpk(float lo, float hi) {
    u32 d;
    asm("v_cvt_pk_bf16_f32 %0, %1, %2" : "=v"(d) : "v"(lo), "v"(hi));
    return d;
}
__device__ __forceinline__ float exp2x(float x) {
    float r;
    asm("v_exp_f32 %0, %1" : "=v"(r) : "v"(x));
    return r;
}
// args pre-scaled: sigmoid arg x -> a = x*log2e ; tanh arg y -> a = y*2*log2e
__device__ __forceinline__ float fsig2(float a) {
    return __builtin_amdgcn_rcpf(1.f + exp2x(-a));
}
__device__ __forceinline__ float ftanh2(float a) {
    return __builtin_fmaf(-2.f, __builtin_amdgcn_rcpf(exp2x(a) + 1.f), 1.f);
}
__device__ __forceinline__ bfx8 pack_bf8(const float* p) {
    float4 a = ((const float4*)p)[0];
    float4 b = ((const float4*)p)[1];
    bfx8 r;
    r[0]=(short)f2bf(a.x); r[1]=(short)f2bf(a.y); r[2]=(short)f2bf(a.z); r[3]=(short)f2bf(a.w);
    r[4]=(short)f2bf(b.x); r[5]=(short)f2bf(b.y); r[6]=(short)f2bf(b.z); r[7]=(short)f2bf(b.w);
    return r;
}
__device__ __forceinline__ bfx8 pack_bf8s(const float* p, float sc) {
    float4 a = ((const float4*)p)[0];
    float4 b = ((const float4*)p)[1];
    bfx8 r;
    r[0]=(short)f2bf(a.x*sc); r[1]=(short)f2bf(a.y*sc); r[2]=(short)f2bf(a.z*sc); r[3]=(short)f2bf(a.w*sc);
    r[4]=(short)f2bf(b.x*sc); r[5]=(short)f2bf(b.y*sc); r[6]=(short)f2bf(b.z*sc); r[7]=(short)f2bf(b.w*sc);
    return r;
}

// ---------------------------------------------------------------------------
// K1: Yb = bf16( X @ W.T )
// ---------------------------------------------------------------------------
__global__ __launch_bounds__(256) void hid_kernel(const float* __restrict__ X,
                                                  const float* __restrict__ W,
                                                  u16* __restrict__ Yb, int N)
{
    __shared__ float sW[64][65];
    int tid = threadIdx.x;
    for (int i = tid; i < 64 * 64; i += 256) sW[i >> 6][i & 63] = W[i];
    __syncthreads();
    int r = blockIdx.x * 4 + (tid >> 6);
    int d = tid & 63;
    if (r >= N) return;
    const float* x = X + (size_t)r * 64;
    float acc = 0.f;
    #pragma unroll
    for (int k = 0; k < 64; ++k) acc += x[k] * sW[d][k];
    Yb[(size_t)r * 64 + d] = f2bf(acc);
}

// ---------------------------------------------------------------------------
// K3: out[r][d] = tanh( U[d][:64].A[r] + U[d][64:].F[r] )
// ---------------------------------------------------------------------------
__global__ __launch_bounds__(256) void upd_kernel(const float* __restrict__ A,
                                                  const float* __restrict__ F,
                                                  const float* __restrict__ U,
                                                  float* __restrict__ out, int N)
{
    __shared__ float sU[64][130];
    int tid = threadIdx.x;
    for (int i = tid; i < 64 * 128; i += 256) sU[i >> 7][i & 127] = U[i];
    __syncthreads();
    int r = blockIdx.x * 4 + (tid >> 6);
    int d = tid & 63;
    if (r >= N) return;
    const float* a = A + (size_t)r * 64;
    const float* f = F + (size_t)r * 64;
    float acc = 0.f;
    #pragma unroll
    for (int k = 0; k < 64; ++k) acc += a[k] * sU[d][k];
    #pragma unroll
    for (int k = 0; k < 64; ++k) acc += f[k] * sU[d][64 + k];
    out[(size_t)r * 64 + d] = tanhf(acc);
}

// ---------------------------------------------------------------------------
// K2 (merged): 1250 blocks; block < nbi -> item side, else user side.
// Round-8 staging (Wi in swizzled LDS, Wh in regs) = proven-best serial core.
// If hG != null: ONE serial pass (scores via shfl + h streamed bf16 to hG),
// then hsum = sum_t alpha*h as a parallel post-phase (no second recurrence).
// Else: classic two-pass. Weights pre-scaled to exp2 domain at staging.
// __launch_bounds__(256,1): any forced min-waves makes the allocator spill.
// ---------------------------------------------------------------------------
__global__ __launch_bounds__(256, 1) void reduce_all(
    const u16*   __restrict__ userB,     // [NU][64] bf16
    const u16*   __restrict__ itemB,     // [NI][64] bf16
    const int*   __restrict__ i_idx,  const int*   __restrict__ i_time,
    const int*   __restrict__ u_idx,  const int*   __restrict__ u_time,
    const float* __restrict__ i_te,   const float* __restrict__ i_tek,
    const float* __restrict__ u_te,   const float* __restrict__ u_tek,
    const float* __restrict__ i_Wi,   const float* __restrict__ i_Wh,
    const float* __restrict__ u_Wi,   const float* __restrict__ u_Wh,
    const float* __restrict__ i_bi,   const float* __restrict__ i_bh,
    const float* __restrict__ u_bi,   const float* __restrict__ u_bh,
    const float* __restrict__ i_glin, const float* __restrict__ u_glin,
    const float* __restrict__ i_agg,  const float* __restrict__ u_agg,
    float* __restrict__ item_out, float* __restrict__ user_out,
    u16* __restrict__ hG, int nbi)
{
    extern __shared__ __align__(16) char smem[];
    u16*   sWI    = (u16*)(smem + OFF_WI);
    u16*   sRIDp  = (u16*)(smem + OFF_RID);
    float* sEF    = (float*)(smem + OFF_EF);
    float* sEB    = (float*)(smem + OFF_EB);
    u8*    sORD   = (u8*)(smem + OFF_ORD);
    u8*    sARE   = (u8*)(smem + OFF_ARE);
    int*   sLASTN = (int*)(smem + OFF_LASTN);

    const bool isU = (int)blockIdx.x >= nbi;
    const int  bid = isU ? ((int)blockIdx.x - nbi) : (int)blockIdx.x;
    const u16*   srcB     = isU ? itemB  : userB;
    const u16*   dstB     = isU ? userB  : itemB;
    const int*   nbr_idx  = isU ? u_idx  : i_idx;
    const int*   nbr_time = isU ? u_time : i_time;
    const float* te       = isU ? u_te   : i_te;
    const float* tek      = isU ? u_tek  : i_tek;
    const float* Wi       = isU ? u_Wi   : i_Wi;
    const float* Wh       = isU ? u_Wh   : i_Wh;
    const float* bi       = isU ? u_bi   : i_bi;
    const float* bh       = isU ? u_bh   : i_bh;
    const float* glin     = isU ? u_glin : i_glin;
    const float* agg      = isU ? u_agg  : i_agg;
    float*       out      = isU ? user_out : item_out;
    const int    sideOff  = isU ? NI : 0;

    const int tid  = threadIdx.x;
    const int lane = tid & 63;
    const int wv   = tid >> 6;            // 0..3
    const int l15  = lane & 15;
    const int grp  = lane >> 4;           // 0..3
    const int lk8  = grp * 8;
    const int nb   = bid * NODES;
    const int dir    = wv >> 1;           // 0=fwd 1=bwd
    const int base16 = (wv & 1) * 16;     // node half owned by this wave
    const bool useHG = (hG != nullptr);

    u16* sHw = (u16*)(smem + OFF_H) + wv * 16 * 72;   // per-wave h [16][72]

    // ---- PH0: times/ids -> stable rank, argmax(first), sorted row ids ----
    int* sTM  = (int*)(smem + OFF_WI);
    int* sNID = sTM + NODES * L;
    for (int p = tid; p < NODES * L; p += 256) {
        sTM[p]  = nbr_time[(size_t)nb * L + p];
        sNID[p] = nbr_idx[(size_t)nb * L + p];
    }
    __syncthreads();
    for (int p = tid; p < NODES * L; p += 256) {
        int m = p / L, l = p - m * L;
        int tl = sTM[p], rank = 0;
        for (int mm = 0; mm < L; ++mm) {
            int tm = sTM[m * L + mm];
            rank += (tm < tl) || (tm == tl && mm < l);
        }
        sORD[m * 52 + rank] = (u8)l;
        sARE[m * 52 + l]    = (u8)(L - 1 - rank);
    }
    if (tid < NODES) {
        int best = 0, bt = sTM[tid * L];
        for (int mm = 1; mm < L; ++mm) {
            int tm = sTM[tid * L + mm];
            if (tm > bt) { bt = tm; best = mm; }
        }
        sLASTN[tid] = sNID[tid * L + best];
    }
    __syncthreads();

    // ---- PH1: sorted row ids (u16) + dst staging (bf16, in H region) ----
    u16* sDST = (u16*)(smem + OFF_H);
    for (int p = tid; p < NODES * L; p += 256) {
        int m = p / L, t = p - m * L;
        sRIDp[m * 52 + t] = (u16)sNID[m * L + sORD[m * 52 + t]];
    }
    for (int p = tid; p < NODES * 64; p += 256) {
        int m = p >> 6, d = p & 63;
        sDST[m * 72 + d] = dstB[(size_t)(nb + m) * 64 + d];
    }
    __syncthreads();

    // ---- PH2a: stage glin^T ----
    u16* sGLT = (u16*)(smem + OFF_WI);             // [128][72]
    for (int p = tid; p < 8192; p += 256) {
        int d = p >> 7, j = p & 127;
        sGLT[j * 72 + d] = f2bf(glin[(size_t)d * 128 + j]);
    }
    __syncthreads();

    // ---- PH2b: v-GEMM (SV=vv regs) + ted GEMM scattered into sEF ----
    float SV[4][4];
    {
        const u16* drow = sDST + (base16 + l15) * 72;
        bfx8 a0 = *(const bfx8*)(drow + lk8);
        bfx8 a1 = *(const bfx8*)(drow + 32 + lk8);
        #pragma unroll
        for (int nt = 0; nt < 4; ++nt) {
            const u16* gr = sGLT + (dir * 64 + nt * 16 + l15) * 72;
            bfx8 b0 = *(const bfx8*)(gr + lk8);
            bfx8 b1 = *(const bfx8*)(gr + 32 + lk8);
            f32x4 acc = {0.f, 0.f, 0.f, 0.f};
            acc = __builtin_amdgcn_mfma_f32_16x16x32_bf16(a0, b0, acc, 0, 0, 0);
            acc = __builtin_amdgcn_mfma_f32_16x16x32_bf16(a1, b1, acc, 0, 0, 0);
            #pragma unroll
            for (int r = 0; r < 4; ++r) SV[nt][r] = acc[r];
        }
    }
    #pragma unroll
    for (int e2 = 0; e2 < 2; ++e2) {
        int it = wv * 2 + e2, mt = it >> 2, nt = it & 3;
        const u16* drow = sDST + (mt * 16 + l15) * 72;
        bfx8 a0 = *(const bfx8*)(drow + lk8);
        bfx8 a1 = *(const bfx8*)(drow + 32 + lk8);
        int j = nt * 16 + l15;
        const float* tr = te + (size_t)(j < L ? j : 0) * 64;
        bfx8 b0 = pack_bf8(tr + lk8);
        bfx8 b1 = pack_bf8(tr + 32 + lk8);
        f32x4 acc = {0.f, 0.f, 0.f, 0.f};
        acc = __builtin_amdgcn_mfma_f32_16x16x32_bf16(a0, b0, acc, 0, 0, 0);
        acc = __builtin_amdgcn_mfma_f32_16x16x32_bf16(a1, b1, acc, 0, 0, 0);
        if (j < L) {
            #pragma unroll
            for (int r = 0; r < 4; ++r) {
                int m = mt * 16 + grp * 4 + r;
                sEF[m * 52 + sORD[m * 52 + (L - 1 - j)]] = acc[r];
            }
        }
    }
    __syncthreads();

    // ---- PH2c: stage Wi (blocked + XOR-swizzled + exp2-prescaled) ----
    for (int p = tid; p < 2 * 192 * 64; p += 256) {
        int kk  = p & 63;
        int row = (p >> 6) % 192;
        int dr  = p / (192 * 64);
        int slot = ((kk & 31) >> 3) ^ ((row >> 1) & 3);
        float sc = ((row >> 6) < 2) ? LOG2E : (2.f * LOG2E);
        sWI[(((dr * 2 + (kk >> 5)) * 192 + row) << 5) + slot * 8 + (kk & 7)]
            = f2bf(Wi[(size_t)(dr * 192 + row) * 64 + kk] * sc);
    }
    // Wh fragments (prescaled) + folded biases in regs
    bfx8 whf[12][2];
    float cb[12], pb[4];
    #pragma unroll
    for (int nt = 0; nt < 12; ++nt) {
        const float* wrow = Wh + (size_t)(dir * 192 + nt * 16 + l15) * 64;
        float sc = (nt < 8) ? LOG2E : (2.f * LOG2E);
        whf[nt][0] = pack_bf8s(wrow + lk8, sc);
        whf[nt][1] = pack_bf8s(wrow + 32 + lk8, sc);
        float bhv = bh[dir * 192 + nt * 16 + l15];
        cb[nt] = (nt < 8) ? (bi[dir * 192 + nt * 16 + l15] + bhv) * LOG2E
                          : bhv * (2.f * LOG2E);
    }
    #pragma unroll
    for (int c = 0; c < 4; ++c)
        pb[c] = bi[dir * 192 + 128 + c * 16 + l15] * (2.f * LOG2E);
    __syncthreads();

    f32x4 xcur[12];
    float hp[4][4];
    const int swoff = (grp ^ ((l15 >> 1) & 3)) * 8;
    const u16* wiA = sWI + (((dir * 2 + 0) * 192 + l15) << 5) + swoff;
    const u16* wiB = sWI + (((dir * 2 + 1) * 192 + l15) << 5) + swoff;
    u16* hGb = nullptr;
    if (useHG)
        hGb = hG + (size_t)(sideOff + nb + base16) * 6400 + dir * 64 + l15 * 4;

    auto produce = [&](bfx8 a0, bfx8 a1) {
        #pragma unroll
        for (int nt = 0; nt < 12; ++nt) {
            bfx8 b0 = *(const bfx8*)(wiA + nt * 512);
            bfx8 b1 = *(const bfx8*)(wiB + nt * 512);
            f32x4 z;
            if (nt >= 8) { float b = pb[nt - 8]; z = (f32x4){b, b, b, b}; }
            else         { z = (f32x4){0.f, 0.f, 0.f, 0.f}; }
            z = __builtin_amdgcn_mfma_f32_16x16x32_bf16(a0, b0, z, 0, 0, 0);
            z = __builtin_amdgcn_mfma_f32_16x16x32_bf16(a1, b1, z, 0, 0, 0);
            xcur[nt] = z;
        }
    };

    auto run_pass = [&](int pass, bool storeH) {
        #pragma unroll
        for (int c = 0; c < 4; ++c)
            #pragma unroll
            for (int r = 0; r < 4; ++r) {
                hp[c][r] = 0.f;
                if (pass == 1) SV[c][r] = 0.f;
                sHw[(grp * 4 + r) * 72 + c * 16 + l15] = 0;
            }
        {   // prologue: xw for s=0
            int tt = dir ? (L - 1) : 0;
            const u16* mrow = srcB + (size_t)sRIDp[(base16 + l15) * 52 + tt] * 64;
            produce(*(const bfx8*)(mrow + lk8), *(const bfx8*)(mrow + 32 + lk8));
        }
        for (int s = 0; s < L; ++s) {
            bfx8 nA, nB;
            if (s + 1 < L) {
                int tt = dir ? (L - 2 - s) : (s + 1);
                const u16* mrow = srcB + (size_t)sRIDp[(base16 + l15) * 52 + tt] * 64;
                nA = *(const bfx8*)(mrow + lk8);
                nB = *(const bfx8*)(mrow + 32 + lk8);
            }
            bfx8 a0 = *(const bfx8*)(sHw + l15 * 72 + lk8);
            bfx8 a1 = *(const bfx8*)(sHw + l15 * 72 + 32 + lk8);
            int t = dir ? (L - 1 - s) : s;
            float al[4];
            if (pass == 1) {
                #pragma unroll
                for (int r = 0; r < 4; ++r)
                    al[r] = sEF[(base16 + grp * 4 + r) * 52 + t];   // alpha
            }
            float pe[4] = {0.f, 0.f, 0.f, 0.f};
            #pragma unroll
            for (int c = 0; c < 4; ++c) {
                f32x4 zr  = {cb[c],     cb[c],     cb[c],     cb[c]};
                f32x4 zz4 = {cb[4 + c], cb[4 + c], cb[4 + c], cb[4 + c]};
                f32x4 zn4 = {cb[8 + c], cb[8 + c], cb[8 + c], cb[8 + c]};
                zr  = __builtin_amdgcn_mfma_f32_16x16x32_bf16(a0, whf[c][0],     zr,  0, 0, 0);
                zr  = __builtin_amdgcn_mfma_f32_16x16x32_bf16(a1, whf[c][1],     zr,  0, 0, 0);
                zz4 = __builtin_amdgcn_mfma_f32_16x16x32_bf16(a0, whf[4 + c][0], zz4, 0, 0, 0);
                zz4 = __builtin_amdgcn_mfma_f32_16x16x32_bf16(a1, whf[4 + c][1], zz4, 0, 0, 0);
                zn4 = __builtin_amdgcn_mfma_f32_16x16x32_bf16(a0, whf[8 + c][0], zn4, 0, 0, 0);
                zn4 = __builtin_amdgcn_mfma_f32_16x16x32_bf16(a1, whf[8 + c][1], zn4, 0, 0, 0);
                #pragma unroll
                for (int r = 0; r < 4; ++r) {
                    float rr = fsig2(xcur[c][r] + zr[r]);
                    float zz = fsig2(xcur[4 + c][r] + zz4[r]);
                    float nn = ftanh2(__builtin_fmaf(rr, zn4[r], xcur[8 + c][r]));
                    float h  = __builtin_fmaf(zz, hp[c][r] - nn, nn);
                    hp[c][r] = h;
                    if (pass == 0) pe[r] += h * SV[c][r];
                    else           SV[c][r] += al[r] * h;
                }
            }
            #pragma unroll
            for (int r = 0; r < 4; ++r) {
                u32 p0 = cvtpk(hp[0][r], hp[1][r]);
                u32 p1 = cvtpk(hp[2][r], hp[3][r]);
                u16* hb = sHw + (grp * 4 + r) * 72 + l15;
                hb[0]  = (u16)p0;  hb[16] = (u16)(p0 >> 16);
                hb[32] = (u16)p1;  hb[48] = (u16)(p1 >> 16);
                if (storeH) {
                    uint2 q; q.x = p0; q.y = p1;
                    *(uint2*)(hGb + (size_t)(grp * 4 + r) * 6400 + s * 128) = q;
                }
            }
            if (pass == 0) {
                #pragma unroll
                for (int r = 0; r < 4; ++r) {
                    #pragma unroll
                    for (int msk = 1; msk < 16; msk <<= 1)
                        pe[r] += __shfl_xor(pe[r], msk, 64);
                }
                if (l15 == 0) {
                    #pragma unroll
                    for (int r = 0; r < 4; ++r) {
                        int idx = (base16 + grp * 4 + r) * 52 + t;
                        if (dir == 0) sEF[idx] += pe[r];
                        else          sEB[idx]  = pe[r];
                    }
                }
            }
            if (s + 1 < L) produce(nA, nB);
        }
    };

    // ---- PH3: serial pass 0 (scores; stream h if hG available) ----
    run_pass(0, useHG);
    __syncthreads();

    // ---- PH4: softmax; alpha overwrites sEF ----
    if (tid < NODES) {
        int m = tid;
        float mx = -1e30f;
        for (int t = 0; t < L; ++t) {
            float v = (sEF[m * 52 + t] + sEB[m * 52 + t]) * 0.125f;
            sEF[m * 52 + t] = v;
            mx = fmaxf(mx, v);
        }
        float sum = 0.f;
        for (int t = 0; t < L; ++t) {
            float ex = __expf(sEF[m * 52 + t] - mx);
            sEF[m * 52 + t] = ex;
            sum += ex;
        }
        float rs = __builtin_amdgcn_rcpf(sum);
        for (int t = 0; t < L; ++t) sEF[m * 52 + t] *= rs;
    }
    __syncthreads();

    // ---- PH5: hsum -> sHS  (post-phase from hG, or second serial pass) ----
    u16* sHS   = (u16*)(smem + OFF_WI);          // [32][136] bf16 hsum f||b
    u16* sA9   = sHS + 32 * 136;                 // [32][136] bf16 hid || last_em
    u16* sTKT  = sA9 + 32 * 136;                 // [64][72]  bf16 te_k^T padded
    u16* sBETA = (u16*)(smem + OFF_EB);          // [32][72]  bf16

    if (useHG) {
        int m2   = tid >> 3;
        int pblk = (tid & 7) << 4;
        int dir2 = pblk >> 6;
        const u16* hp2 = hG + (size_t)(sideOff + nb + m2) * 6400 + pblk;
        float acc[16];
        #pragma unroll
        for (int i = 0; i < 16; ++i) acc[i] = 0.f;
        for (int s = 0; s < L; ++s) {
            float a = sEF[m2 * 52 + (dir2 ? (L - 1 - s) : s)];
            const uint4* q = (const uint4*)(hp2 + (size_t)s * 128);
            uint4 v0 = q[0], v1 = q[1];
            acc[0]  += a * bflo(v0.x); acc[1]  += a * bfhi(v0.x);
            acc[2]  += a * bflo(v0.y); acc[3]  += a * bfhi(v0.y);
            acc[4]  += a * bflo(v0.z); acc[5]  += a * bfhi(v0.z);
            acc[6]  += a * bflo(v0.w); acc[7]  += a * bfhi(v0.w);
            acc[8]  += a * bflo(v1.x); acc[9]  += a * bfhi(v1.x);
            acc[10] += a * bflo(v1.y); acc[11] += a * bfhi(v1.y);
            acc[12] += a * bflo(v1.z); acc[13] += a * bfhi(v1.z);
            acc[14] += a * bflo(v1.w); acc[15] += a * bfhi(v1.w);
        }
        u16* row = sHS + m2 * 136 + dir2 * 64;
        #pragma unroll
        for (int i = 0; i < 16; ++i) {
            int pd = (pblk + i) & 63;
            row[(pd & 3) * 16 + (pd >> 2)] = f2bf(acc[i]);
        }
    } else {
        run_pass(1, false);
        __syncthreads();
        #pragma unroll
        for (int c = 0; c < 4; ++c)
            #pragma unroll
            for (int r = 0; r < 4; ++r)
                sHS[(base16 + grp * 4 + r) * 136 + dir * 64 + c * 16 + l15] = f2bf(SV[c][r]);
    }

    // ---- PH6: epilogue staging ----
    if (tid < NODES) {
        for (int t = 0; t < L; ++t)
            sBETA[tid * 72 + sARE[tid * 52 + t]] = f2bf(sEF[tid * 52 + t]);
        for (int j = L; j < 64; ++j) sBETA[tid * 72 + j] = 0;
    }
    for (int p = tid; p < 4096; p += 256) {
        int j = p >> 6, d = p & 63;
        sTKT[d * 72 + j] = (j < L) ? f2bf(tek[(size_t)j * 64 + d]) : (u16)0;
    }
    for (int p = tid; p < NODES * 64; p += 256) {
        int m = p >> 6, d = p & 63;
        sA9[m * 136 + 64 + d] = srcB[(size_t)sLASTN[m] * 64 + d];
    }
    __syncthreads();

    // hid[m][d] = glin[d][:].hsum[m] + te_k^T[d][:].beta[m]
    #pragma unroll
    for (int e2 = 0; e2 < 2; ++e2) {
        int it = wv * 2 + e2, mt = it >> 2, nt = it & 3;
        bfx8 aH[4], aB[2];
        #pragma unroll
        for (int kt = 0; kt < 4; ++kt)
            aH[kt] = *(const bfx8*)(sHS + (mt * 16 + l15) * 136 + kt * 32 + lk8);
        #pragma unroll
        for (int kt = 0; kt < 2; ++kt)
            aB[kt] = *(const bfx8*)(sBETA + (mt * 16 + l15) * 72 + kt * 32 + lk8);
        f32x4 acc = {0.f, 0.f, 0.f, 0.f};
        #pragma unroll
        for (int kt = 0; kt < 4; ++kt) {
            bfx8 b = pack_bf8(glin + (size_t)(nt * 16 + l15) * 128 + kt * 32 + lk8);
            acc = __builtin_amdgcn_mfma_f32_16x16x32_bf16(aH[kt], b, acc, 0, 0, 0);
        }
        #pragma unroll
        for (int kt = 0; kt < 2; ++kt) {
            bfx8 b = *(const bfx8*)(sTKT + (nt * 16 + l15) * 72 + kt * 32 + lk8);
            acc = __builtin_amdgcn_mfma_f32_16x16x32_bf16(aB[kt], b, acc, 0, 0, 0);
        }
        #pragma unroll
        for (int r = 0; r < 4; ++r)
            sA9[(mt * 16 + grp * 4 + r) * 136 + nt * 16 + l15] = f2bf(acc[r]);
    }
    __syncthreads();

    // out[m][d] = agg[d][:64].hid[m] + agg[d][64:].last_em[m]
    #pragma unroll
    for (int e2 = 0; e2 < 2; ++e2) {
        int it = wv * 2 + e2, mt = it >> 2, nt = it & 3;
        bfx8 aA[4];
        #pragma unroll
        for (int kt = 0; kt < 4; ++kt)
            aA[kt] = *(const bfx8*)(sA9 + (mt * 16 + l15) * 136 + kt * 32 + lk8);
        f32x4 acc = {0.f, 0.f, 0.f, 0.f};
        #pragma unroll
        for (int kt = 0; kt < 4; ++kt) {
            bfx8 b = pack_bf8(agg + (size_t)(nt * 16 + l15) * 128 + kt * 32 + lk8);
            acc = __builtin_amdgcn_mfma_f32_16x16x32_bf16(aA[kt], b, acc, 0, 0, 0);
        }
        #pragma unroll
        for (int r = 0; r < 4; ++r)
            out[(size_t)(nb + mt * 16 + grp * 4 + r) * 64 + nt * 16 + l15] = acc[r];
    }
}

// ---------------------------------------------------------------------------
extern "C" void kernel_launch(void* const* d_in, const int* in_sizes, int n_in,
                              void* d_out, int out_size, void* d_ws, size_t ws_size,
                              hipStream_t stream)
{
    const float* user_feat     = (const float*)d_in[0];
    const float* item_feat     = (const float*)d_in[1];
    const int*   item_nbr_idx  = (const int*)d_in[2];
    const int*   item_nbr_time = (const int*)d_in[3];
    const int*   user_nbr_idx  = (const int*)d_in[4];
    const int*   user_nbr_time = (const int*)d_in[5];
    const float* W_user        = (const float*)d_in[6];
    const float* W_item        = (const float*)d_in[7];
    const float* u_te          = (const float*)d_in[8];
    const float* u_te_k        = (const float*)d_in[9];
    const float* i_te          = (const float*)d_in[10];
    const float* i_te_k        = (const float*)d_in[11];
    const float* gru_u_Wi      = (const float*)d_in[12];
    const float* gru_u_Wh      = (const float*)d_in[13];
    const float* gru_u_bi      = (const float*)d_in[14];
    const float* gru_u_bh      = (const float*)d_in[15];
    const float* gru_i_Wi      = (const float*)d_in[16];
    const float* gru_i_Wh      = (const float*)d_in[17];
    const float* gru_i_bi      = (const float*)d_in[18];
    const float* gru_i_bh      = (const float*)d_in[19];
    const float* gru_lin_u     = (const float*)d_in[20];
    const float* gru_lin_i     = (const float*)d_in[21];
    const float* agg_u         = (const float*)d_in[22];
    const float* agg_i         = (const float*)d_in[23];
    const float* upd_u         = (const float*)d_in[24];
    const float* upd_i         = (const float*)d_in[25];

    float* ws       = (float*)d_ws;
    float* user_agg = ws;
    float* item_agg = user_agg + NU * 64;
    u16*   userB    = (u16*)(item_agg + NI * 64);
    u16*   itemB    = userB + NU * 64;
    u16*   hGbuf    = itemB + NI * 64;

    size_t need = (size_t)(NU + NI) * 64 * 4      // aggs
                + (size_t)(NU + NI) * 64 * 2      // bf16 hid
                + (size_t)(NU + NI) * 6400 * 2;   // hG: [40000][50][128] bf16
    u16* hG = (ws_size >= need) ? hGbuf : (u16*)nullptr;

    (void)hipFuncSetAttribute((const void*)reduce_all,
                              hipFuncAttributeMaxDynamicSharedMemorySize, SMEM_SZ);

    hid_kernel<<<NU / 4, 256, 0, stream>>>(user_feat, W_user, userB, NU);
    hid_kernel<<<NI / 4, 256, 0, stream>>>(item_feat, W_item, itemB, NI);

    const int NBI = NI / NODES;     // 625 item-side blocks, then 625 user-side
    reduce_all<<<NBI + NU / NODES, 256, SMEM_SZ, stream>>>(
        userB, itemB,
        item_nbr_idx, item_nbr_time, user_nbr_idx, user_nbr_time,
        i_te, i_te_k, u_te, u_te_k,
        gru_i_Wi, gru_i_Wh, gru_u_Wi, gru_u_Wh,
        gru_i_bi, gru_i_bh, gru_u_bi, gru_u_bh,
        gru_lin_i, gru_lin_u, agg_i, agg_u,
        item_agg, user_agg, hG, NBI);

    float* out = (float*)d_out;
    upd_kernel<<<NU / 4, 256, 0, stream>>>(user_agg, user_feat, upd_u, out, NU);
    upd_kernel<<<NI / 4, 256, 0, stream>>>(item_agg, item_feat, upd_i, out + NU * 64, NI);
}